// Round 2
// baseline (187.590 us; speedup 1.0000x reference)
//
#include <hip/hip_runtime.h>
#include <hip/hip_bf16.h>

#define SEQL 2048
#define DMODEL 1024

typedef short bf16x8 __attribute__((ext_vector_type(8)));
typedef short bf16x4 __attribute__((ext_vector_type(4)));
typedef float f32x4 __attribute__((ext_vector_type(4)));
typedef float f32x16 __attribute__((ext_vector_type(16)));
typedef unsigned short u16;

__device__ __forceinline__ u16 f2bf(float f) {
    union { float f; unsigned u; } v; v.f = f;
    unsigned r = v.u + 0x7FFFu + ((v.u >> 16) & 1u);
    return (u16)(r >> 16);
}

// native 2^x (single v_exp_f32)
__device__ __forceinline__ float fexp2(float x) {
#if __has_builtin(__builtin_amdgcn_exp2f)
    return __builtin_amdgcn_exp2f(x);
#else
    return exp2f(x);
#endif
}

// (1/sqrt(d_model)) * log2(e) : fold expf's log2e multiply into the scale
#define SCALE2 0.04508422f

// pack 2 f32 -> 1 u32 of 2 bf16 (v_cvt_pk_bf16_f32 via compiler)
__device__ __forceinline__ unsigned pkbf(float lo, float hi_) {
    __hip_bfloat162 hh = __float22bfloat162_rn(make_float2(lo, hi_));
    return *(unsigned*)&hh;
}

// v_permlane32_swap_b32: a.hi32lanes <-> b.lo32lanes
// after: a = {a.lanes0-31, b.lanes0-31}, b = {a.lanes32-63, b.lanes32-63}
__device__ __forceinline__ void plswap(unsigned &a, unsigned &b) {
    asm volatile("v_permlane32_swap_b32 %0, %1" : "+v"(a), "+v"(b));
}

// async 16B global->LDS copy (global_load_lds_dwordx4)
__device__ __forceinline__ void async16(u16* lds, const u16* g) {
    __builtin_amdgcn_global_load_lds(
        (const __attribute__((address_space(1))) unsigned int*)g,
        (__attribute__((address_space(3))) unsigned int*)lds,
        16, 0, 0);
}

// ============================================================================
// 32x32x16 fragment convention: lane = m + 32*hi (hi=lane>>5), k = hi*8 + j.
// A/B frag = 8 bf16 per lane. C/D: col = lane&31, row = (reg&3)+8*(reg>>2)+4*hi.
//
// K  image per (n,h,kt64): frag (kh*4+f), kh=key>>5, f=d>>4;
//                          elem: (key&31 + 32*((d>>3)&1))*8 + (d&7)
// Vt image per (n,h,kt64): frag (kg*2+dh), kg=key>>4, dh=d>>5;
//                          elem: (d&31 + 32*((key>>3)&1))*8 + (key&7)
// W  image per (cb,kt64):  16x16 frag-order (unchanged, fc uses 16x16x32)
// X  image per (rb128,kt64): 16x16 frag-order (unchanged)
// ============================================================================

#define TSTR 72

__global__ __launch_bounds__(256) void pack_all(
    const float* __restrict__ kg, const float* __restrict__ wg,
    const float* __restrict__ vg, const int* __restrict__ mg,
    u16* __restrict__ kb, u16* __restrict__ wb, u16* __restrict__ vtb,
    float* __restrict__ maskf)
{
    __shared__ __align__(16) u16 T[64 * TSTR];
    const int b = blockIdx.x, t = threadIdx.x;
    u16 o[8];
    if (b < 2048) {
        const int e0 = (b * 256 + t) * 8;
        const int n = e0 >> 21;
        const int s = (e0 >> 10) & 2047;
        const int dm = e0 & 1023, h = dm >> 6, d0 = dm & 63;
        const float4 x0 = *(const float4*)(kg + e0);
        const float4 x1 = *(const float4*)(kg + e0 + 4);
        o[0]=f2bf(x0.x); o[1]=f2bf(x0.y); o[2]=f2bf(x0.z); o[3]=f2bf(x0.w);
        o[4]=f2bf(x1.x); o[5]=f2bf(x1.y); o[6]=f2bf(x1.z); o[7]=f2bf(x1.w);
        const int kt = s >> 6, key = s & 63, kh = key >> 5, m = key & 31;
        const int f = d0 >> 4, h2 = (d0 >> 3) & 1;
        u16* dst = kb + ((size_t)((n * 16 + h) * 32 + kt)) * 4096
                      + (kh * 4 + f) * 512 + (m + 32 * h2) * 8;
        *(bf16x8*)dst = *(bf16x8*)o;
    } else if (b < 2560) {
        const int e0 = ((b - 2048) * 256 + t) * 8;
        const int col = e0 >> 10, k0 = e0 & 1023;
        const float4 x0 = *(const float4*)(wg + e0);
        const float4 x1 = *(const float4*)(wg + e0 + 4);
        o[0]=f2bf(x0.x); o[1]=f2bf(x0.y); o[2]=f2bf(x0.z); o[3]=f2bf(x0.w);
        o[4]=f2bf(x1.x); o[5]=f2bf(x1.y); o[6]=f2bf(x1.z); o[7]=f2bf(x1.w);
        const int cb = col >> 6, cj = (col >> 4) & 3, m = col & 15;
        const int kt = k0 >> 6, f = (k0 >> 5) & 1, qd = (k0 >> 3) & 3;
        u16* dst = wb + ((size_t)((cb * 16 + kt) * 8 + cj * 2 + f)) * 512
                      + (m + 16 * qd) * 8;
        *(bf16x8*)dst = *(bf16x8*)o;
    } else if (b < 3584) {
        const int bb = b - 2560;
        const int kt = bb & 31, h = (bb >> 5) & 15, n = bb >> 9;
        {
            const int s = t >> 2, d0 = (t & 3) * 16;
            const float* src = vg + ((size_t)(n * SEQL + kt * 64 + s) * DMODEL) + h * 64 + d0;
            u16 w16[16];
            #pragma unroll
            for (int j = 0; j < 16; ++j) w16[j] = f2bf(src[j]);
            *(bf16x8*)&T[s * TSTR + d0]     = *(bf16x8*)&w16[0];
            *(bf16x8*)&T[s * TSTR + d0 + 8] = *(bf16x8*)&w16[8];
        }
        __syncthreads();
        {
            const int d = t >> 2, k0 = (t & 3) * 16;
            u16 w16[16];
            #pragma unroll
            for (int j = 0; j < 16; ++j) w16[j] = T[(k0 + j) * TSTR + d];
            const int kgp = t & 3;            // key-group (16 keys)
            const int dh = d >> 5, m = d & 31;
            u16* base = vtb + ((size_t)((n * 16 + h) * 32 + kt)) * 4096
                            + (kgp * 2 + dh) * 512;
            *(bf16x8*)(base + m * 8)        = *(bf16x8*)&w16[0];  // keys k0..k0+7  (hi=0)
            *(bf16x8*)(base + (m + 32) * 8) = *(bf16x8*)&w16[8];  // keys k0+8..+15 (hi=1)
        }
    } else {
        #pragma unroll
        for (int i = 0; i < 16; ++i) {
            const int idx = t * 16 + i;
            maskf[idx] = mg[idx] ? 0.0f : -1.0e5f;
        }
    }
}

// ---------- attention: 32x32x16 MFMA, swapped QK^T, in-register P (T12) ------
#define OSPLIT 4194304   // fp32 elems per O-partial split (16 MB)
#define LSPLIT 65536     // fp32 elems per l-partial split

template<int NSPLIT>
__global__ __launch_bounds__(256) void attn_kernel(
    const float* __restrict__ qg, const u16* __restrict__ kb,
    const u16* __restrict__ vtb, const float* __restrict__ maskf,
    u16* __restrict__ xb, float* __restrict__ opart, float* __restrict__ lpart)
{
    // K dbuf 2x4096 | V dbuf 2x4096 | lsum 128 f32  (33.28 KB)
    __shared__ __align__(16) u16 SM[16640];
    u16* const K_lds = SM;            // [2][4096]
    u16* const V_lds = SM + 8192;     // [2][4096]
    float* const LS  = (float*)(SM + 16384);

    const int blk = blockIdx.x;            // qblk(16) x h(16) x n(2) x split
    const int qblk = blk & 15;
    const int h = (blk >> 4) & 15;
    const int n = (blk >> 8) & 1;
    const int split = blk >> 9;
    const int tid = threadIdx.x;
    const int wave = tid >> 6, lane = tid & 63;
    const int l31 = lane & 31, hi = lane >> 5;
    const int q0 = qblk * 128;

    const u16* ksrc0 = kb  + ((size_t)(n * 16 + h)) * 131072;  // 32 kt * 4096
    const u16* vsrc0 = vtb + ((size_t)(n * 16 + h)) * 131072;
    const float* mrow = maskf + n * SEQL;

    const int ktlo = split * (32 / NSPLIT);
    const int kthi = ktlo + (32 / NSPLIT);

    // prologue: stage tile ktlo into buffer 0 (overlaps the Q f2bf work below)
    {
        const u16* ks = ksrc0 + (size_t)ktlo * 4096;
        const u16* vs = vsrc0 + (size_t)ktlo * 4096;
        #pragma unroll
        for (int i = 0; i < 2; ++i) {
            const int ch = tid + i * 256;          // 512 chunks of 16B each
            async16(&K_lds[ch * 8], ks + ch * 8);
            async16(&V_lds[ch * 8], vs + ch * 8);
        }
    }

    // Q B-frags: q = q0 + wave*32 + l31 ; d = h*64 + f*16 + hi*8 + j
    bf16x8 qf[4];
    {
        const float* qp = qg + ((size_t)(n * SEQL + q0 + wave * 32 + l31) * DMODEL)
                        + h * 64 + hi * 8;
        #pragma unroll
        for (int f = 0; f < 4; ++f) {
            const float4 a = *(const float4*)(qp + f * 16);
            const float4 c = *(const float4*)(qp + f * 16 + 4);
            u16* dst = (u16*)&qf[f];
            dst[0]=f2bf(a.x); dst[1]=f2bf(a.y); dst[2]=f2bf(a.z); dst[3]=f2bf(a.w);
            dst[4]=f2bf(c.x); dst[5]=f2bf(c.y); dst[6]=f2bf(c.z); dst[7]=f2bf(c.w);
        }
    }

    f32x16 oacc[2];
    #pragma unroll
    for (int dh = 0; dh < 2; ++dh)
        #pragma unroll
        for (int i = 0; i < 16; ++i) oacc[dh][i] = 0.f;
    float lsum = 0.f;

    __syncthreads();   // drain prologue loads

    for (int kt = ktlo; kt < kthi; ++kt) {
        const int cur = (kt - ktlo) & 1;
        const u16* const Kc = K_lds + cur * 4096;
        const u16* const Vc = V_lds + cur * 4096;

        // issue next tile's loads into the other buffer (async, no wait)
        if (kt + 1 < kthi) {
            const int nxt = cur ^ 1;
            const u16* ks = ksrc0 + (size_t)(kt + 1) * 4096;
            const u16* vs = vsrc0 + (size_t)(kt + 1) * 4096;
            #pragma unroll
            for (int i = 0; i < 2; ++i) {
                const int ch = tid + i * 256;
                async16(&K_lds[nxt * 4096 + ch * 8], ks + ch * 8);
                async16(&V_lds[nxt * 4096 + ch * 8], vs + ch * 8);
            }
        }

        #pragma unroll
        for (int kh = 0; kh < 2; ++kh) {
            // S^T = K Q^T over this 32-key half: col=q(l31), row=key per reg map
            const bf16x8 kf0 = *(const bf16x8*)&Kc[(kh * 4 + 0) * 512 + lane * 8];
            const bf16x8 kf1 = *(const bf16x8*)&Kc[(kh * 4 + 1) * 512 + lane * 8];
            const bf16x8 kf2 = *(const bf16x8*)&Kc[(kh * 4 + 2) * 512 + lane * 8];
            const bf16x8 kf3 = *(const bf16x8*)&Kc[(kh * 4 + 3) * 512 + lane * 8];
            f32x16 sacc;
            #pragma unroll
            for (int i = 0; i < 16; ++i) sacc[i] = 0.f;
            __builtin_amdgcn_s_setprio(1);
            sacc = __builtin_amdgcn_mfma_f32_32x32x16_bf16(kf0, qf[0], sacc, 0, 0, 0);
            sacc = __builtin_amdgcn_mfma_f32_32x32x16_bf16(kf1, qf[1], sacc, 0, 0, 0);
            sacc = __builtin_amdgcn_mfma_f32_32x32x16_bf16(kf2, qf[2], sacc, 0, 0, 0);
            sacc = __builtin_amdgcn_mfma_f32_32x32x16_bf16(kf3, qf[3], sacc, 0, 0, 0);
            __builtin_amdgcn_s_setprio(0);

            // key for reg i: kh*32 + 8*(i>>2) + 4*hi + (i&3)
            const float* mp = mrow + kt * 64 + kh * 32 + 4 * hi;
            const f32x4 m0 = *(const f32x4*)(mp);
            const f32x4 m1 = *(const f32x4*)(mp + 8);
            const f32x4 m2 = *(const f32x4*)(mp + 16);
            const f32x4 m3 = *(const f32x4*)(mp + 24);
            float e[16];
            #pragma unroll
            for (int r = 0; r < 4; ++r) {
                e[r]      = fexp2(fmaf(sacc[r],      SCALE2, m0[r]));
                e[4 + r]  = fexp2(fmaf(sacc[4 + r],  SCALE2, m1[r]));
                e[8 + r]  = fexp2(fmaf(sacc[8 + r],  SCALE2, m2[r]));
                e[12 + r] = fexp2(fmaf(sacc[12 + r], SCALE2, m3[r]));
            }
            lsum += ((e[0]+e[1])+(e[2]+e[3])) + ((e[4]+e[5])+(e[6]+e[7]))
                  + ((e[8]+e[9])+(e[10]+e[11])) + ((e[12]+e[13])+(e[14]+e[15]));

            // pack reg-pairs, then permlane32_swap builds PV A-frags in-register
            unsigned w0 = pkbf(e[0],  e[1]),  w1 = pkbf(e[2],  e[3]);
            unsigned w2 = pkbf(e[4],  e[5]),  w3 = pkbf(e[6],  e[7]);
            unsigned w4 = pkbf(e[8],  e[9]),  w5 = pkbf(e[10], e[11]);
            unsigned w6 = pkbf(e[12], e[13]), w7 = pkbf(e[14], e[15]);

            // key-group kg = kh*2 + 0 (keys kh*32 + 0..15)
            plswap(w0, w2);   // w0 -> j01 word, w2 -> j45 word
            plswap(w1, w3);   // w1 -> j23 word, w3 -> j67 word
            union { unsigned u[4]; bf16x8 v; } A0;
            A0.u[0] = w0; A0.u[1] = w1; A0.u[2] = w2; A0.u[3] = w3;
            {
                const int kg = kh * 2 + 0;
                const bf16x8 vf0 = *(const bf16x8*)&Vc[(kg * 2 + 0) * 512 + lane * 8];
                const bf16x8 vf1 = *(const bf16x8*)&Vc[(kg * 2 + 1) * 512 + lane * 8];
                __builtin_amdgcn_s_setprio(1);
                oacc[0] = __builtin_amdgcn_mfma_f32_32x32x16_bf16(A0.v, vf0, oacc[0], 0, 0, 0);
                oacc[1] = __builtin_amdgcn_mfma_f32_32x32x16_bf16(A0.v, vf1, oacc[1], 0, 0, 0);
                __builtin_amdgcn_s_setprio(0);
            }
            // key-group kg = kh*2 + 1 (keys kh*32 + 16..31)
            plswap(w4, w6);
            plswap(w5, w7);
            union { unsigned u[4]; bf16x8 v; } A1;
            A1.u[0] = w4; A1.u[1] = w5; A1.u[2] = w6; A1.u[3] = w7;
            {
                const int kg = kh * 2 + 1;
                const bf16x8 vf2 = *(const bf16x8*)&Vc[(kg * 2 + 0) * 512 + lane * 8];
                const bf16x8 vf3 = *(const bf16x8*)&Vc[(kg * 2 + 1) * 512 + lane * 8];
                __builtin_amdgcn_s_setprio(1);
                oacc[0] = __builtin_amdgcn_mfma_f32_32x32x16_bf16(A1.v, vf2, oacc[0], 0, 0, 0);
                oacc[1] = __builtin_amdgcn_mfma_f32_32x32x16_bf16(A1.v, vf3, oacc[1], 0, 0, 0);
                __builtin_amdgcn_s_setprio(0);
            }
        }

        __syncthreads();   // drains vmcnt(0): next tile landed during compute
    }

    // full row-sum for q = l31: combine the two key-halves held by lane^32
    const float s_full = lsum + __shfl_xor(lsum, 32);

    if (NSPLIT == 1) {
        // broadcast 1/l to the oacc row distribution via tiny LDS bounce
        if (lane < 32) LS[wave * 32 + l31] = s_full;
        __syncthreads();
        f32x4 rv[4];
        #pragma unroll
        for (int g = 0; g < 4; ++g)
            rv[g] = *(const f32x4*)&LS[wave * 32 + g * 8 + 4 * hi];
        #pragma unroll
        for (int dh = 0; dh < 2; ++dh) {
            const int c = l31;
            #pragma unroll
            for (int g = 0; g < 4; ++g)
                #pragma unroll
                for (int r = 0; r < 4; ++r) {
                    const int row = n * SEQL + q0 + wave * 32 + g * 8 + 4 * hi + r;
                    const int rb = row >> 7, rt = (row >> 4) & 7, m = row & 15;
                    xb[((size_t)((rb * 16 + h) * 16 + rt * 2 + dh)) * 512
                       + (m + 16 * ((c >> 3) & 3)) * 8 + (c & 7)]
                        = f2bf(oacc[dh][g * 4 + r] / rv[g][r]);
                }
        }
    } else {
        #pragma unroll
        for (int dh = 0; dh < 2; ++dh) {
            #pragma unroll
            for (int g = 0; g < 4; ++g)
                #pragma unroll
                for (int r = 0; r < 4; ++r) {
                    const int q = q0 + wave * 32 + g * 8 + 4 * hi + r;
                    opart[(size_t)split * OSPLIT + (size_t)(n * SEQL + q) * DMODEL
                          + h * 64 + dh * 32 + l31] = oacc[dh][g * 4 + r];
                }
        }
        if (lane < 32)
            lpart[split * LSPLIT + (n * SEQL + q0 + wave * 32 + l31) * 16 + h] = s_full;
    }
}

// ---------- split-K reduce + normalize -> frag-ordered bf16 X ----------
template<int NSPLIT>
__global__ __launch_bounds__(256) void reduce_norm(
    const float* __restrict__ opart, const float* __restrict__ lpart,
    u16* __restrict__ xb)
{
    const int gid = blockIdx.x * 256 + threadIdx.x;   // 524288 threads
    const int e0 = gid * 8;
    const int row = e0 >> 10, k0 = e0 & 1023, h = k0 >> 6;
    float lsum = 0.f;
    #pragma unroll
    for (int s = 0; s < NSPLIT; ++s) lsum += lpart[s * LSPLIT + row * 16 + h];
    const float rinv = 1.0f / lsum;
    float a[8] = {0.f,0.f,0.f,0.f,0.f,0.f,0.f,0.f};
    #pragma unroll
    for (int s = 0; s < NSPLIT; ++s) {
        const float4 x0 = *(const float4*)(opart + (size_t)s * OSPLIT + e0);
        const float4 x1 = *(const float4*)(opart + (size_t)s * OSPLIT + e0 + 4);
        a[0]+=x0.x; a[1]+=x0.y; a[2]+=x0.z; a[3]+=x0.w;
        a[4]+=x1.x; a[5]+=x1.y; a[6]+=x1.z; a[7]+=x1.w;
    }
    u16 o[8];
    #pragma unroll
    for (int j = 0; j < 8; ++j) o[j] = f2bf(a[j] * rinv);
    // frag-ordered X address (16x16 convention for fc)
    const int rb = row >> 7, rt = (row >> 4) & 7, m = row & 15;
    const int kt = k0 >> 6, f = (k0 >> 5) & 1, qd = (k0 >> 3) & 3;
    *(bf16x8*)(xb + ((size_t)((rb * 16 + kt) * 16 + rt * 2 + f)) * 512
                  + (m + 16 * qd) * 8) = *(bf16x8*)o;
}

// ---------- FC: out = X @ W^T + b, 128x64 tile, BK=64, frag-ordered ----------
__global__ __launch_bounds__(256) void fc_kernel(
    const u16* __restrict__ xb, const u16* __restrict__ wb,
    const float* __restrict__ bias, float* __restrict__ out)
{
    // X dbuf 2x8192 | W dbuf 2x4096 (48 KB)
    __shared__ __align__(16) u16 SM[24576];
    u16* const X_lds = SM;            // [2][8192]
    u16* const W_lds = SM + 16384;    // [2][4096]

    const int blk = blockIdx.x;          // 32 rowblocks x 16 colblocks = 512
    const int cb = blk & 15, rb = blk >> 4;
    const int tid = threadIdx.x;
    const int wave = tid >> 6, lane = tid & 63;
    const int lrow = lane & 15, quad = lane >> 4;

    const u16* xs0 = xb + ((size_t)rb * 16) * 8192;
    const u16* ws0 = wb + ((size_t)cb * 16) * 4096;

    f32x4 acc[2][4];
    #pragma unroll
    for (int ri = 0; ri < 2; ++ri)
        #pragma unroll
        for (int cj = 0; cj < 4; ++cj) acc[ri][cj] = (f32x4){0.f, 0.f, 0.f, 0.f};

    {
        #pragma unroll
        for (int i = 0; i < 4; ++i) {
            const int ch = tid + i * 256;          // 1024 chunks
            async16(&X_lds[ch * 8], xs0 + ch * 8);
        }
        #pragma unroll
        for (int i = 0; i < 2; ++i) {
            const int ch = tid + i * 256;          // 512 chunks
            async16(&W_lds[ch * 8], ws0 + ch * 8);
        }
    }
    __syncthreads();

    for (int kt = 0; kt < 16; ++kt) {
        const int cur = kt & 1;
        const u16* const Xc = X_lds + cur * 8192;
        const u16* const Wc = W_lds + cur * 4096;

        if (kt + 1 < 16) {
            const int nxt = cur ^ 1;
            const u16* xs = xs0 + (size_t)(kt + 1) * 8192;
            const u16* ws = ws0 + (size_t)(kt + 1) * 4096;
            #pragma unroll
            for (int i = 0; i < 4; ++i) {
                const int ch = tid + i * 256;
                async16(&X_lds[nxt * 8192 + ch * 8], xs + ch * 8);
            }
            #pragma unroll
            for (int i = 0; i < 2; ++i) {
                const int ch = tid + i * 256;
                async16(&W_lds[nxt * 4096 + ch * 8], ws + ch * 8);
            }
        }

        bf16x8 af[2][2];
        #pragma unroll
        for (int ri = 0; ri < 2; ++ri) {
            af[ri][0] = *(const bf16x8*)&Xc[((wave * 2 + ri) * 2 + 0) * 512 + lane * 8];
            af[ri][1] = *(const bf16x8*)&Xc[((wave * 2 + ri) * 2 + 1) * 512 + lane * 8];
        }
        #pragma unroll
        for (int cj = 0; cj < 4; ++cj) {
            const bf16x8 bf0 = *(const bf16x8*)&Wc[(cj * 2 + 0) * 512 + lane * 8];
            const bf16x8 bf1 = *(const bf16x8*)&Wc[(cj * 2 + 1) * 512 + lane * 8];
            #pragma unroll
            for (int ri = 0; ri < 2; ++ri) {
                acc[ri][cj] = __builtin_amdgcn_mfma_f32_16x16x32_bf16(af[ri][0], bf0, acc[ri][cj], 0, 0, 0);
                acc[ri][cj] = __builtin_amdgcn_mfma_f32_16x16x32_bf16(af[ri][1], bf1, acc[ri][cj], 0, 0, 0);
            }
        }

        __syncthreads();
    }

    const int row0 = rb * 128, col0 = cb * 64;
    #pragma unroll
    for (int ri = 0; ri < 2; ++ri)
        #pragma unroll
        for (int cj = 0; cj < 4; ++cj) {
            const int col = col0 + cj * 16 + lrow;
            const float bv = bias[col];
            #pragma unroll
            for (int r = 0; r < 4; ++r)
                out[(size_t)(row0 + wave * 32 + ri * 16 + quad * 4 + r) * DMODEL + col] = acc[ri][cj][r] + bv;
        }
}

extern "C" void kernel_launch(void* const* d_in, const int* in_sizes, int n_in,
                              void* d_out, int out_size, void* d_ws, size_t ws_size,
                              hipStream_t stream) {
    const float* q   = (const float*)d_in[0];
    const float* k   = (const float*)d_in[1];
    const float* v   = (const float*)d_in[2];
    const int*   m   = (const int*)d_in[3];
    const float* fcw = (const float*)d_in[4];
    const float* fcb = (const float*)d_in[5];
    float* out = (float*)d_out;

    char* ws = (char*)d_ws;
    u16*   kbuf  = (u16*)(ws);                     // 8 MB  frag-ordered K
    u16*   vtbuf = (u16*)(ws + (8u  << 20));       // 8 MB  frag-ordered V^T
    u16*   wbuf  = (u16*)(ws + (16u << 20));       // 2 MB  frag-ordered W
    u16*   xbuf  = (u16*)(ws + (18u << 20));       // 8 MB  frag-ordered X
    float* maskf = (float*)(ws + (26u << 20));     // 16 KB float bias [2][2048]
    float* opart = (float*)(ws + (27u << 20));     // 32 MB fp32 [2][4096][1024]
    float* lpart = (float*)(ws + (59u << 20));     // 512 KB fp32 [2][4096][16]
    const bool split2 = ws_size >= (60u << 20);

    pack_all<<<dim3(3585), dim3(256), 0, stream>>>(k, fcw, v, m, kbuf, wbuf, vtbuf, maskf);
    if (split2) {
        attn_kernel<2><<<dim3(1024), dim3(256), 0, stream>>>(q, kbuf, vtbuf, maskf, xbuf, opart, lpart);
        reduce_norm<2><<<dim3(2048), dim3(256), 0, stream>>>(opart, lpart, xbuf);
    } else {
        attn_kernel<1><<<dim3(512), dim3(256), 0, stream>>>(q, kbuf, vtbuf, maskf, xbuf, opart, lpart);
    }
    fc_kernel<<<dim3(512), dim3(256), 0, stream>>>(xbuf, wbuf, fcb, out);
}

// Round 3
// 171.366 us; speedup vs baseline: 1.0947x; 1.0947x over previous
//
#include <hip/hip_runtime.h>
#include <hip/hip_bf16.h>

#define SEQL 2048
#define DMODEL 1024

typedef short bf16x8 __attribute__((ext_vector_type(8)));
typedef short bf16x4 __attribute__((ext_vector_type(4)));
typedef float f32x4 __attribute__((ext_vector_type(4)));
typedef unsigned short u16;

__device__ __forceinline__ u16 f2bf(float f) {
    union { float f; unsigned u; } v; v.f = f;
    unsigned r = v.u + 0x7FFFu + ((v.u >> 16) & 1u);
    return (u16)(r >> 16);
}

// native 2^x (single v_exp_f32)
__device__ __forceinline__ float fexp2(float x) {
#if __has_builtin(__builtin_amdgcn_exp2f)
    return __builtin_amdgcn_exp2f(x);
#else
    return exp2f(x);
#endif
}

// (1/sqrt(d_model)) * log2(e) : fold expf's log2e multiply into the scale
#define SCALE2 0.04508422f

// async 16B global->LDS copy (global_load_lds_dwordx4)
__device__ __forceinline__ void async16(u16* lds, const u16* g) {
    __builtin_amdgcn_global_load_lds(
        (const __attribute__((address_space(1))) unsigned int*)g,
        (__attribute__((address_space(3))) unsigned int*)lds,
        16, 0, 0);
}

// ============================================================================
// Fragment-ordered layouts (16x16x32 convention). Frag = 64 lanes x 8 elems.
// lane = m + 16*quad, elems j=0..7 where (m = non-k index, k = quad*8+j).
//
// K  image per (n,h,kt64): [st 0..3][f 0..1] frag; key=st*16+m, d=f*32+q*8+j
// Vt image per (n,h,kt64): [t4 0..3][kk 0..1] frag; d=t4*16+m, key=kk*32+q*8+j
// W  image per (cb,kt64):  [cj 0..3][f 0..1] frag; col=cj*16+m, k=f*32+q*8+j
// X  image per (rb128,kt64): [rt 0..7][f 0..1] frag; row=rt*16+m, k=f*32+q*8+j
// ============================================================================

#define TSTR 72

__global__ __launch_bounds__(256) void pack_all(
    const float* __restrict__ kg, const float* __restrict__ wg,
    const float* __restrict__ vg, const int* __restrict__ mg,
    u16* __restrict__ kb, u16* __restrict__ wb, u16* __restrict__ vtb,
    float* __restrict__ maskf)
{
    __shared__ __align__(16) u16 T[64 * TSTR];
    const int b = blockIdx.x, t = threadIdx.x;
    u16 o[8];
    if (b < 2048) {
        const int e0 = (b * 256 + t) * 8;
        const int n = e0 >> 21;
        const int s = (e0 >> 10) & 2047;
        const int dm = e0 & 1023, h = dm >> 6, d0 = dm & 63;
        const float4 x0 = *(const float4*)(kg + e0);
        const float4 x1 = *(const float4*)(kg + e0 + 4);
        o[0]=f2bf(x0.x); o[1]=f2bf(x0.y); o[2]=f2bf(x0.z); o[3]=f2bf(x0.w);
        o[4]=f2bf(x1.x); o[5]=f2bf(x1.y); o[6]=f2bf(x1.z); o[7]=f2bf(x1.w);
        const int kt = s >> 6, st = (s >> 4) & 3, m = s & 15;
        const int f = d0 >> 5, qd = (d0 >> 3) & 3;
        u16* dst = kb + ((size_t)((n * 16 + h) * 32 + kt)) * 4096
                      + (st * 2 + f) * 512 + (m + 16 * qd) * 8;
        *(bf16x8*)dst = *(bf16x8*)o;
    } else if (b < 2560) {
        const int e0 = ((b - 2048) * 256 + t) * 8;
        const int col = e0 >> 10, k0 = e0 & 1023;
        const float4 x0 = *(const float4*)(wg + e0);
        const float4 x1 = *(const float4*)(wg + e0 + 4);
        o[0]=f2bf(x0.x); o[1]=f2bf(x0.y); o[2]=f2bf(x0.z); o[3]=f2bf(x0.w);
        o[4]=f2bf(x1.x); o[5]=f2bf(x1.y); o[6]=f2bf(x1.z); o[7]=f2bf(x1.w);
        const int cb = col >> 6, cj = (col >> 4) & 3, m = col & 15;
        const int kt = k0 >> 6, f = (k0 >> 5) & 1, qd = (k0 >> 3) & 3;
        u16* dst = wb + ((size_t)((cb * 16 + kt) * 8 + cj * 2 + f)) * 512
                      + (m + 16 * qd) * 8;
        *(bf16x8*)dst = *(bf16x8*)o;
    } else if (b < 3584) {
        const int bb = b - 2560;
        const int kt = bb & 31, h = (bb >> 5) & 15, n = bb >> 9;
        {
            const int s = t >> 2, d0 = (t & 3) * 16;
            const float* src = vg + ((size_t)(n * SEQL + kt * 64 + s) * DMODEL) + h * 64 + d0;
            u16 w16[16];
            #pragma unroll
            for (int j = 0; j < 16; ++j) w16[j] = f2bf(src[j]);
            *(bf16x8*)&T[s * TSTR + d0]     = *(bf16x8*)&w16[0];
            *(bf16x8*)&T[s * TSTR + d0 + 8] = *(bf16x8*)&w16[8];
        }
        __syncthreads();
        {
            const int d = t >> 2, k0 = (t & 3) * 16;
            u16 w16[16];
            #pragma unroll
            for (int j = 0; j < 16; ++j) w16[j] = T[(k0 + j) * TSTR + d];
            const int t4 = d >> 4, dr = d & 15;
            u16* base = vtb + ((size_t)((n * 16 + h) * 32 + kt)) * 4096;
            #pragma unroll
            for (int g = 0; g < 2; ++g) {
                const int key0 = k0 + g * 8;
                const int kk = key0 >> 5, qk = (key0 >> 3) & 3;
                *(bf16x8*)(base + (t4 * 2 + kk) * 512 + (dr + 16 * qk) * 8)
                    = *(bf16x8*)&w16[g * 8];
            }
        }
    } else {
        #pragma unroll
        for (int i = 0; i < 16; ++i) {
            const int idx = t * 16 + i;
            maskf[idx] = mg[idx] ? 0.0f : -1.0e5f;
        }
    }
}

// ---------- attention: QT=128, KT=64, S^T trick, IN-BLOCK split-K -----------
// 8 waves: waves 0-3 process kt 0..15, waves 4-7 process kt 16..31, each half
// with its own single-buffered K/V LDS region (R0's proven 2-barrier loop).
// Final combine via LDS; normalized frag-ordered X written directly.
// Removes the opart/lpart/reduce_norm pipeline entirely.
__global__ __launch_bounds__(512) void attn_fused(
    const float* __restrict__ qg, const u16* __restrict__ kb,
    const u16* __restrict__ vtb, const float* __restrict__ maskf,
    u16* __restrict__ xb)
{
    // K [2 halves][4096] | V [2][4096] | P [8 waves][2048]  = 64 KB
    __shared__ __align__(16) u16 SM[32768];

    const int blk = blockIdx.x;            // qblk(16) x h(16) x n(2) = 512
    const int qblk = blk & 15;
    const int h = (blk >> 4) & 15;
    const int n = blk >> 8;
    const int tid = threadIdx.x;
    const int wave = tid >> 6, lane = tid & 63;
    const int half = wave >> 2, w4 = wave & 3;
    const int tloc = tid & 255;            // thread id within half
    const int lrow = lane & 15, quad = lane >> 4;
    const int q0 = qblk * 128;

    u16* const K_lds = SM + half * 4096;
    u16* const V_lds = SM + 8192 + half * 4096;
    u16* const P_lds = SM + 16384 + wave * 2048;

    const u16* ksrc = kb  + ((size_t)(n * 16 + h)) * 131072 + (size_t)half * 65536;
    const u16* vsrc = vtb + ((size_t)(n * 16 + h)) * 131072 + (size_t)half * 65536;
    const float* mrow = maskf + n * SEQL + half * 1024;

    // Q fragments ([q=lane&15][d=quad*8+j]); 2 q-tiles per wave
    bf16x8 qf[2][2];
    #pragma unroll
    for (int qi = 0; qi < 2; ++qi) {
        const float* qp = qg + ((size_t)(n * SEQL + q0 + w4 * 32 + qi * 16 + lrow) * DMODEL) + h * 64 + quad * 8;
        #pragma unroll
        for (int f = 0; f < 2; ++f) {
            const float4 a = *(const float4*)(qp + f * 32);
            const float4 c = *(const float4*)(qp + f * 32 + 4);
            u16* dst = (u16*)&qf[qi][f];
            dst[0]=f2bf(a.x); dst[1]=f2bf(a.y); dst[2]=f2bf(a.z); dst[3]=f2bf(a.w);
            dst[4]=f2bf(c.x); dst[5]=f2bf(c.y); dst[6]=f2bf(c.z); dst[7]=f2bf(c.w);
        }
    }

    bf16x8 onesf;
    #pragma unroll
    for (int j = 0; j < 8; ++j) ((u16*)&onesf)[j] = 0x3F80;

    f32x4 oacc[2][4];
    f32x4 lacc[2];
    #pragma unroll
    for (int qi = 0; qi < 2; ++qi) {
        lacc[qi] = (f32x4){0.f, 0.f, 0.f, 0.f};
        #pragma unroll
        for (int t4 = 0; t4 < 4; ++t4) oacc[qi][t4] = (f32x4){0.f, 0.f, 0.f, 0.f};
    }

    for (int i = 0; i < 16; ++i) {
        __syncthreads();
        {
            const u16* ks = ksrc + (size_t)i * 4096;
            const u16* vs = vsrc + (size_t)i * 4096;
            #pragma unroll
            for (int c = 0; c < 2; ++c) {
                const int ch = tloc + c * 256;     // 512 chunks of 16B per half
                async16(&K_lds[ch * 8], ks + ch * 8);
                async16(&V_lds[ch * 8], vs + ch * 8);
            }
        }
        __syncthreads();

        // S^T = K Q^T : C col = q (lane&15), C rows = key (quad*4+r)
        #pragma unroll
        for (int st = 0; st < 4; ++st) {
            const bf16x8 kf0 = *(const bf16x8*)&K_lds[(st * 2 + 0) * 512 + lane * 8];
            const bf16x8 kf1 = *(const bf16x8*)&K_lds[(st * 2 + 1) * 512 + lane * 8];
            const f32x4 mv = *(const f32x4*)&mrow[i * 64 + st * 16 + quad * 4];
            // P-write frag coords for key = st*16 + quad*4 + r
            const int kk = st >> 1;
            const int qk = (st & 1) * 2 + (quad >> 1);
            const int j0 = (quad & 1) * 4;
            #pragma unroll
            for (int qi = 0; qi < 2; ++qi) {
                f32x4 sa = (f32x4){0.f, 0.f, 0.f, 0.f};
                sa = __builtin_amdgcn_mfma_f32_16x16x32_bf16(kf0, qf[qi][0], sa, 0, 0, 0);
                sa = __builtin_amdgcn_mfma_f32_16x16x32_bf16(kf1, qf[qi][1], sa, 0, 0, 0);
                float e0v = fexp2(fmaf(sa[0], SCALE2, mv[0]));
                float e1v = fexp2(fmaf(sa[1], SCALE2, mv[1]));
                float e2v = fexp2(fmaf(sa[2], SCALE2, mv[2]));
                float e3v = fexp2(fmaf(sa[3], SCALE2, mv[3]));
                __hip_bfloat162 h0 = __float22bfloat162_rn(make_float2(e0v, e1v));
                __hip_bfloat162 h1 = __float22bfloat162_rn(make_float2(e2v, e3v));
                union { unsigned u[2]; bf16x4 v; } pk;
                pk.u[0] = *(unsigned*)&h0;
                pk.u[1] = *(unsigned*)&h1;
                *(bf16x4*)&P_lds[(qi * 2 + kk) * 512 + (lrow + 16 * qk) * 8 + j0] = pk.v;
            }
        }
        asm volatile("s_waitcnt lgkmcnt(0)" ::: "memory");

        bf16x8 vf[4][2];
        #pragma unroll
        for (int t4 = 0; t4 < 4; ++t4) {
            vf[t4][0] = *(const bf16x8*)&V_lds[(t4 * 2 + 0) * 512 + lane * 8];
            vf[t4][1] = *(const bf16x8*)&V_lds[(t4 * 2 + 1) * 512 + lane * 8];
        }
        #pragma unroll
        for (int qi = 0; qi < 2; ++qi) {
            const bf16x8 pf0 = *(const bf16x8*)&P_lds[(qi * 2 + 0) * 512 + lane * 8];
            const bf16x8 pf1 = *(const bf16x8*)&P_lds[(qi * 2 + 1) * 512 + lane * 8];
            lacc[qi] = __builtin_amdgcn_mfma_f32_16x16x32_bf16(pf0, onesf, lacc[qi], 0, 0, 0);
            lacc[qi] = __builtin_amdgcn_mfma_f32_16x16x32_bf16(pf1, onesf, lacc[qi], 0, 0, 0);
            #pragma unroll
            for (int t4 = 0; t4 < 4; ++t4) {
                oacc[qi][t4] = __builtin_amdgcn_mfma_f32_16x16x32_bf16(pf0, vf[t4][0], oacc[qi][t4], 0, 0, 0);
                oacc[qi][t4] = __builtin_amdgcn_mfma_f32_16x16x32_bf16(pf1, vf[t4][1], oacc[qi][t4], 0, 0, 0);
            }
        }
    }

    // ---- in-block split-K combine ----
    __syncthreads();   // all waves done with K/V/P LDS
    float* const Pf = (float*)(SM + 16384);   // 8192 f32 (32 KB) partial oacc
    float* const Lf = (float*)SM;             // 2048 f32 (8 KB)  partial lacc
    if (half) {
        float* dst = Pf + (size_t)(w4 * 64 + lane) * 32;
        float* ld  = Lf + (size_t)(w4 * 64 + lane) * 8;
        #pragma unroll
        for (int qi = 0; qi < 2; ++qi) {
            *(f32x4*)(ld + qi * 4) = lacc[qi];
            #pragma unroll
            for (int t4 = 0; t4 < 4; ++t4)
                *(f32x4*)(dst + qi * 16 + t4 * 4) = oacc[qi][t4];
        }
    }
    __syncthreads();
    if (!half) {
        const float* src = Pf + (size_t)(w4 * 64 + lane) * 32;
        const float* ls  = Lf + (size_t)(w4 * 64 + lane) * 8;
        #pragma unroll
        for (int qi = 0; qi < 2; ++qi) {
            lacc[qi] += *(const f32x4*)(ls + qi * 4);
            #pragma unroll
            for (int t4 = 0; t4 < 4; ++t4)
                oacc[qi][t4] += *(const f32x4*)(src + qi * 16 + t4 * 4);
        }
        // normalize + write frag-ordered bf16 X (same mapping as the verified
        // opart -> reduce_norm path: row=..+quad*4+r, col=h*64+t4*16+lrow)
        #pragma unroll
        for (int qi = 0; qi < 2; ++qi)
            #pragma unroll
            for (int r = 0; r < 4; ++r) {
                const float rinv = 1.0f / lacc[qi][r];
                const int row = n * SEQL + q0 + w4 * 32 + qi * 16 + quad * 4 + r;
                const int rb = row >> 7, rt = (row >> 4) & 7, m = row & 15;
                #pragma unroll
                for (int t4 = 0; t4 < 4; ++t4) {
                    const int f = t4 >> 1;
                    const int qd = (t4 & 1) * 2 + (lrow >> 3);
                    xb[((size_t)((rb * 16 + h) * 16 + rt * 2 + f)) * 512
                       + (m + 16 * qd) * 8 + (lrow & 7)] = f2bf(oacc[qi][t4][r] * rinv);
                }
            }
    }
}

// ---------- FC: out = X @ W^T + b, 128x64 tile, BK=64, frag-ordered ----------
// 2-phase pipelined: double-buffered X/W, prefetch issued before compute.
__global__ __launch_bounds__(256) void fc_kernel(
    const u16* __restrict__ xb, const u16* __restrict__ wb,
    const float* __restrict__ bias, float* __restrict__ out)
{
    // X dbuf 2x8192 | W dbuf 2x4096 (48 KB)
    __shared__ __align__(16) u16 SM[24576];
    u16* const X_lds = SM;            // [2][8192]
    u16* const W_lds = SM + 16384;    // [2][4096]

    const int blk = blockIdx.x;          // 32 rowblocks x 16 colblocks = 512
    const int cb = blk & 15, rb = blk >> 4;
    const int tid = threadIdx.x;
    const int wave = tid >> 6, lane = tid & 63;
    const int lrow = lane & 15, quad = lane >> 4;

    const u16* xs0 = xb + ((size_t)rb * 16) * 8192;
    const u16* ws0 = wb + ((size_t)cb * 16) * 4096;

    f32x4 acc[2][4];
    #pragma unroll
    for (int ri = 0; ri < 2; ++ri)
        #pragma unroll
        for (int cj = 0; cj < 4; ++cj) acc[ri][cj] = (f32x4){0.f, 0.f, 0.f, 0.f};

    {
        #pragma unroll
        for (int i = 0; i < 4; ++i) {
            const int ch = tid + i * 256;          // 1024 chunks
            async16(&X_lds[ch * 8], xs0 + ch * 8);
        }
        #pragma unroll
        for (int i = 0; i < 2; ++i) {
            const int ch = tid + i * 256;          // 512 chunks
            async16(&W_lds[ch * 8], ws0 + ch * 8);
        }
    }
    __syncthreads();

    for (int kt = 0; kt < 16; ++kt) {
        const int cur = kt & 1;
        const u16* const Xc = X_lds + cur * 8192;
        const u16* const Wc = W_lds + cur * 4096;

        if (kt + 1 < 16) {
            const int nxt = cur ^ 1;
            const u16* xs = xs0 + (size_t)(kt + 1) * 8192;
            const u16* ws = ws0 + (size_t)(kt + 1) * 4096;
            #pragma unroll
            for (int i = 0; i < 4; ++i) {
                const int ch = tid + i * 256;
                async16(&X_lds[nxt * 8192 + ch * 8], xs + ch * 8);
            }
            #pragma unroll
            for (int i = 0; i < 2; ++i) {
                const int ch = tid + i * 256;
                async16(&W_lds[nxt * 4096 + ch * 8], ws + ch * 8);
            }
        }

        bf16x8 af[2][2];
        #pragma unroll
        for (int ri = 0; ri < 2; ++ri) {
            af[ri][0] = *(const bf16x8*)&Xc[((wave * 2 + ri) * 2 + 0) * 512 + lane * 8];
            af[ri][1] = *(const bf16x8*)&Xc[((wave * 2 + ri) * 2 + 1) * 512 + lane * 8];
        }
        #pragma unroll
        for (int cj = 0; cj < 4; ++cj) {
            const bf16x8 bf0 = *(const bf16x8*)&Wc[(cj * 2 + 0) * 512 + lane * 8];
            const bf16x8 bf1 = *(const bf16x8*)&Wc[(cj * 2 + 1) * 512 + lane * 8];
            #pragma unroll
            for (int ri = 0; ri < 2; ++ri) {
                acc[ri][cj] = __builtin_amdgcn_mfma_f32_16x16x32_bf16(af[ri][0], bf0, acc[ri][cj], 0, 0, 0);
                acc[ri][cj] = __builtin_amdgcn_mfma_f32_16x16x32_bf16(af[ri][1], bf1, acc[ri][cj], 0, 0, 0);
            }
        }

        __syncthreads();
    }

    const int row0 = rb * 128, col0 = cb * 64;
    #pragma unroll
    for (int ri = 0; ri < 2; ++ri)
        #pragma unroll
        for (int cj = 0; cj < 4; ++cj) {
            const int col = col0 + cj * 16 + lrow;
            const float bv = bias[col];
            #pragma unroll
            for (int r = 0; r < 4; ++r)
                out[(size_t)(row0 + wave * 32 + ri * 16 + quad * 4 + r) * DMODEL + col] = acc[ri][cj][r] + bv;
        }
}

extern "C" void kernel_launch(void* const* d_in, const int* in_sizes, int n_in,
                              void* d_out, int out_size, void* d_ws, size_t ws_size,
                              hipStream_t stream) {
    const float* q   = (const float*)d_in[0];
    const float* k   = (const float*)d_in[1];
    const float* v   = (const float*)d_in[2];
    const int*   m   = (const int*)d_in[3];
    const float* fcw = (const float*)d_in[4];
    const float* fcb = (const float*)d_in[5];
    float* out = (float*)d_out;

    char* ws = (char*)d_ws;
    u16*   kbuf  = (u16*)(ws);                     // 8 MB  frag-ordered K
    u16*   vtbuf = (u16*)(ws + (8u  << 20));       // 8 MB  frag-ordered V^T
    u16*   wbuf  = (u16*)(ws + (16u << 20));       // 2 MB  frag-ordered W
    u16*   xbuf  = (u16*)(ws + (18u << 20));       // 8 MB  frag-ordered X
    float* maskf = (float*)(ws + (26u << 20));     // 16 KB float bias [2][2048]

    pack_all<<<dim3(3585), dim3(256), 0, stream>>>(k, fcw, v, m, kbuf, wbuf, vtbuf, maskf);
    attn_fused<<<dim3(512), dim3(512), 0, stream>>>(q, kbuf, vtbuf, maskf, xbuf);
    fc_kernel<<<dim3(512), dim3(256), 0, stream>>>(xbuf, wbuf, fcb, out);
}